// Round 1
// baseline (2557.162 us; speedup 1.0000x reference)
//
#include <hip/hip_runtime.h>
#include <stdint.h>

#define B_ 64
#define T_ 16
#define D0 1024
#define H_ 2048
#define G4 8192  // 4*H

typedef unsigned short u16;
typedef __attribute__((ext_vector_type(4))) float f32x4;
typedef __attribute__((ext_vector_type(8))) short bf16x8;

__device__ __forceinline__ u16 f2bf(float f) {
  unsigned int u = __builtin_bit_cast(unsigned int, f);
  unsigned int r = (u + 0x7FFFu + ((u >> 16) & 1u)) >> 16;
  return (u16)r;
}

__device__ __forceinline__ void gld_lds16(const void* g, void* l) {
  __builtin_amdgcn_global_load_lds(
      (const __attribute__((address_space(1))) void*)g,
      (__attribute__((address_space(3))) void*)l, 16, 0, 0);
}

// ---------------- fp32 -> bf16 bulk conversion (RTN) ----------------
__global__ __launch_bounds__(256) void k_f32_to_bf16(
    const float* __restrict__ src, u16* __restrict__ dst, int n8) {
  int i = blockIdx.x * 256 + threadIdx.x;
  int stride = gridDim.x * 256;
  const float4* s = (const float4*)src;
  uint4* d = (uint4*)dst;
  for (; i < n8; i += stride) {
    float4 a = s[2 * i], b = s[2 * i + 1];
    uint4 o;
    o.x = f2bf(a.x) | ((unsigned)f2bf(a.y) << 16);
    o.y = f2bf(a.z) | ((unsigned)f2bf(a.w) << 16);
    o.z = f2bf(b.x) | ((unsigned)f2bf(b.y) << 16);
    o.w = f2bf(b.z) | ((unsigned)f2bf(b.w) << 16);
    d[i] = o;
  }
}

// ---------------- combined bias: b_ih + b_hh, 4 layers ----------------
__global__ __launch_bounds__(256) void k_bias(
    const float* __restrict__ bih0, const float* __restrict__ bhh0,
    const float* __restrict__ bihr, const float* __restrict__ bhhr,
    float* __restrict__ bias) {
  int i = blockIdx.x * 256 + threadIdx.x;
  if (i >= 4 * G4) return;
  int l = i >> 13, j = i & (G4 - 1);
  float a = (l == 0) ? bih0[j] : bihr[(l - 1) * G4 + j];
  float b = (l == 0) ? bhh0[j] : bhhr[(l - 1) * G4 + j];
  bias[i] = a + b;
}

// ---------------- stage x [B,T,D0] fp32 -> A [t*B+b, D0] bf16 ----------------
__global__ __launch_bounds__(256) void k_stage_x(
    const float* __restrict__ x, u16* __restrict__ A) {
  int i = blockIdx.x * 256 + threadIdx.x;  // over (B*T*D0)/8 chunks
  if (i >= (B_ * T_ * D0) / 8) return;
  int chunk = i & (D0 / 8 - 1);
  int r = i >> 7;  // r = t*B + b
  int b = r & (B_ - 1), t = r >> 6;
  const float4* s = (const float4*)(x + ((size_t)(b * T_ + t)) * D0 + chunk * 8);
  float4 a0 = s[0], a1 = s[1];
  uint4 o;
  o.x = f2bf(a0.x) | ((unsigned)f2bf(a0.y) << 16);
  o.y = f2bf(a0.z) | ((unsigned)f2bf(a0.w) << 16);
  o.z = f2bf(a1.x) | ((unsigned)f2bf(a1.y) << 16);
  o.w = f2bf(a1.z) | ((unsigned)f2bf(a1.w) << 16);
  *(uint4*)(A + (size_t)r * D0 + chunk * 8) = o;
}

// ---------------- input-projection GEMM ----------------
// C[M=1024, N=8192] = A[1024,K] * W[8192,K]^T + bias[N]
// 128x128 tile, 256 thr (4 waves 2x2), BK=32, global_load_lds staging.
__global__ __launch_bounds__(256) void k_gemm_xi(
    const u16* __restrict__ A, const u16* __restrict__ W,
    const float* __restrict__ bias, float* __restrict__ C, int K) {
  __shared__ __align__(16) u16 sA[128 * 32];
  __shared__ __align__(16) u16 sB[128 * 32];
  const int tid = threadIdx.x;
  const int wave = tid >> 6;
  const int lane = tid & 63;
  const int m0 = blockIdx.y * 128;
  const int n0 = blockIdx.x * 128;
  const int wr = wave >> 1, wc = wave & 1;
  const int lr = lane & 15;
  const int kc = (lane >> 4) * 8;
  const int rowA = tid >> 2, colk = (tid & 3) * 8;

  f32x4 acc[4][4] = {};

  for (int k0 = 0; k0 < K; k0 += 32) {
#pragma unroll
    for (int iss = 0; iss < 2; ++iss) {
      gld_lds16(A + (size_t)(m0 + iss * 64 + rowA) * K + k0 + colk,
                sA + (iss * 64 + wave * 16) * 32);
      gld_lds16(W + (size_t)(n0 + iss * 64 + rowA) * K + k0 + colk,
                sB + (iss * 64 + wave * 16) * 32);
    }
    __syncthreads();
    bf16x8 a[4], b[4];
#pragma unroll
    for (int m = 0; m < 4; ++m)
      a[m] = *(const bf16x8*)&sA[(wr * 64 + m * 16 + lr) * 32 + kc];
#pragma unroll
    for (int n = 0; n < 4; ++n)
      b[n] = *(const bf16x8*)&sB[(wc * 64 + n * 16 + lr) * 32 + kc];
#pragma unroll
    for (int m = 0; m < 4; ++m)
#pragma unroll
      for (int n = 0; n < 4; ++n)
        acc[m][n] = __builtin_amdgcn_mfma_f32_16x16x32_bf16(a[m], b[n], acc[m][n], 0, 0, 0);
    __syncthreads();
  }

#pragma unroll
  for (int n = 0; n < 4; ++n) {
    int col = n0 + wc * 64 + n * 16 + lr;
    float bv = bias[col];
#pragma unroll
    for (int m = 0; m < 4; ++m) {
      int rbase = m0 + wr * 64 + m * 16 + ((lane >> 4) << 2);
#pragma unroll
      for (int j = 0; j < 4; ++j)
        C[(size_t)(rbase + j) * G4 + col] = acc[m][n][j] + bv;
    }
  }
}

// ---------------- fused recurrent step + LSTM cell ----------------
// grid 64 blocks: block owns 32 hidden units (all 4 gates), M=64 batch.
// gates = h_{t-1} @ Whh^T + xi[t];  c,h update;  h -> bf16 into next A buf.
__global__ __launch_bounds__(256) void k_lstm_step(
    const u16* __restrict__ hA, const u16* __restrict__ W,
    const float* __restrict__ xi, float* __restrict__ c,
    u16* __restrict__ hout, float* __restrict__ out32, int t) {
  __shared__ __align__(16) u16 sA[64 * 32];
  __shared__ __align__(16) u16 sB[128 * 32];
  __shared__ float gbuf[4 * 64 * 32];
  const int tid = threadIdx.x;
  const int wave = tid >> 6;  // = gate index
  const int lane = tid & 63;
  const int n0 = blockIdx.x * 32;
  const int lr = lane & 15;
  const int kc = (lane >> 4) * 8;
  const int rowA = tid >> 2, colk = (tid & 3) * 8;

  f32x4 acc[4][2] = {};

  for (int k0 = 0; k0 < H_; k0 += 32) {
    gld_lds16(hA + (size_t)rowA * H_ + k0 + colk, sA + wave * 16 * 32);
#pragma unroll
    for (int iss = 0; iss < 2; ++iss) {
      int lrow = iss * 64 + rowA;
      int grow = (lrow >> 5) * H_ + n0 + (lrow & 31);  // gate*H + hidden
      gld_lds16(W + (size_t)grow * H_ + k0 + colk,
                sB + (iss * 64 + wave * 16) * 32);
    }
    __syncthreads();
    bf16x8 a[4], b[2];
#pragma unroll
    for (int m = 0; m < 4; ++m)
      a[m] = *(const bf16x8*)&sA[(m * 16 + lr) * 32 + kc];
#pragma unroll
    for (int n = 0; n < 2; ++n)
      b[n] = *(const bf16x8*)&sB[(wave * 32 + n * 16 + lr) * 32 + kc];
#pragma unroll
    for (int m = 0; m < 4; ++m)
#pragma unroll
      for (int n = 0; n < 2; ++n)
        acc[m][n] = __builtin_amdgcn_mfma_f32_16x16x32_bf16(a[m], b[n], acc[m][n], 0, 0, 0);
    __syncthreads();
  }

  // raw gate values (+xi) into LDS: gbuf[gate][b][hid_local]
#pragma unroll
  for (int n = 0; n < 2; ++n) {
    int nl = n * 16 + lr;
#pragma unroll
    for (int m = 0; m < 4; ++m) {
      int bbase = m * 16 + ((lane >> 4) << 2);
#pragma unroll
      for (int j = 0; j < 4; ++j) {
        int brow = bbase + j;
        float v = acc[m][n][j] +
                  xi[(size_t)(t * B_ + brow) * G4 + wave * H_ + n0 + nl];
        gbuf[(wave * 64 + brow) * 32 + nl] = v;
      }
    }
  }
  __syncthreads();

  // LSTM cell update: 64*32 = 2048 elements, 8 per thread
#pragma unroll
  for (int j = 0; j < 8; ++j) {
    int e = tid + 256 * j;
    int b = e >> 5, nl = e & 31;
    float iv = gbuf[(0 * 64 + b) * 32 + nl];
    float fv = gbuf[(1 * 64 + b) * 32 + nl];
    float gv = gbuf[(2 * 64 + b) * 32 + nl];
    float ov = gbuf[(3 * 64 + b) * 32 + nl];
    iv = 1.f / (1.f + expf(-iv));
    fv = 1.f / (1.f + expf(-fv));
    gv = tanhf(gv);
    ov = 1.f / (1.f + expf(-ov));
    size_t ci = (size_t)b * H_ + n0 + nl;
    float cv = fv * c[ci] + iv * gv;
    c[ci] = cv;
    float hv = ov * tanhf(cv);
    hout[(size_t)(t * B_ + b) * H_ + n0 + nl] = f2bf(hv);
    if (out32 != nullptr) out32[((size_t)b * T_ + t) * H_ + n0 + nl] = hv;
  }
}

extern "C" void kernel_launch(void* const* d_in, const int* in_sizes, int n_in,
                              void* d_out, int out_size, void* d_ws, size_t ws_size,
                              hipStream_t stream) {
  const float* x    = (const float*)d_in[0];
  const float* wih0 = (const float*)d_in[1];
  const float* whh0 = (const float*)d_in[2];
  const float* bih0 = (const float*)d_in[3];
  const float* bhh0 = (const float*)d_in[4];
  const float* wihr = (const float*)d_in[5];
  const float* whhr = (const float*)d_in[6];
  const float* bihr = (const float*)d_in[7];
  const float* bhhr = (const float*)d_in[8];
  float* out = (float*)d_out;

  char* ws = (char*)d_ws;
  size_t off = 0;
  auto alloc = [&](size_t bytes) -> void* {
    void* p = ws + off;
    off += (bytes + 255) & ~(size_t)255;
    return p;
  };
  u16*   wih_b  = (u16*)alloc(((size_t)G4 * D0 + 3ull * G4 * H_) * 2);  // layer0 then r
  u16*   whh_b  = (u16*)alloc(4ull * G4 * H_ * 2);
  float* bias   = (float*)alloc(4ull * G4 * 4);
  float* xi     = (float*)alloc((size_t)T_ * B_ * G4 * 4);
  u16*   Ax     = (u16*)alloc((size_t)T_ * B_ * D0 * 2);
  u16*   bufA   = (u16*)alloc((size_t)T_ * B_ * H_ * 2);
  u16*   bufB   = (u16*)alloc((size_t)T_ * B_ * H_ * 2);
  u16*   h0     = (u16*)alloc((size_t)B_ * H_ * 2);
  float* cbuf   = (float*)alloc((size_t)B_ * H_ * 4);

  u16* wih_r_b = wih_b + (size_t)G4 * D0;

  auto cgrid = [](int n8) { int g = (n8 + 255) / 256; return g > 8192 ? 8192 : g; };

  int n8;
  n8 = (G4 * D0) / 8;
  k_f32_to_bf16<<<cgrid(n8), 256, 0, stream>>>(wih0, wih_b, n8);
  n8 = (3 * G4 * H_) / 8;
  k_f32_to_bf16<<<cgrid(n8), 256, 0, stream>>>(wihr, wih_r_b, n8);
  n8 = (G4 * H_) / 8;
  k_f32_to_bf16<<<cgrid(n8), 256, 0, stream>>>(whh0, whh_b, n8);
  n8 = (3 * G4 * H_) / 8;
  k_f32_to_bf16<<<cgrid(n8), 256, 0, stream>>>(whhr, whh_b + (size_t)G4 * H_, n8);

  k_bias<<<(4 * G4 + 255) / 256, 256, 0, stream>>>(bih0, bhh0, bihr, bhhr, bias);
  k_stage_x<<<((B_ * T_ * D0) / 8 + 255) / 256, 256, 0, stream>>>(x, Ax);
  hipMemsetAsync(h0, 0, (size_t)B_ * H_ * 2, stream);

  const u16* Ain = Ax;
  for (int l = 0; l < 4; ++l) {
    hipMemsetAsync(cbuf, 0, (size_t)B_ * H_ * 4, stream);
    const u16* W_ih = (l == 0) ? wih_b : (wih_r_b + (size_t)(l - 1) * G4 * H_);
    int K = (l == 0) ? D0 : H_;
    dim3 g(G4 / 128, (T_ * B_) / 128);
    k_gemm_xi<<<g, 256, 0, stream>>>(Ain, W_ih, bias + (size_t)l * G4, xi, K);

    const u16* Whh = whh_b + (size_t)l * G4 * H_;
    u16* Aout = (l & 1) ? bufB : bufA;
    for (int t = 0; t < T_; ++t) {
      const u16* hprev = (t == 0) ? h0 : (Aout + (size_t)(t - 1) * B_ * H_);
      k_lstm_step<<<H_ / 32, 256, 0, stream>>>(
          hprev, Whh, xi, cbuf, Aout, (l == 3) ? out : nullptr, t);
    }
    Ain = Aout;
  }
}

// Round 3
// 2060.719 us; speedup vs baseline: 1.2409x; 1.2409x over previous
//
#include <hip/hip_runtime.h>
#include <stdint.h>

#define B_ 64
#define T_ 16
#define D0 1024
#define H_ 2048
#define G4 8192  // 4*H
#define NB 256   // persistent blocks (one per CU)

typedef unsigned short u16;
typedef __attribute__((ext_vector_type(4))) float f32x4;
typedef __attribute__((ext_vector_type(8))) short bf16x8;

__device__ __forceinline__ u16 f2bf(float f) {
  unsigned int u = __builtin_bit_cast(unsigned int, f);
  unsigned int r = (u + 0x7FFFu + ((u >> 16) & 1u)) >> 16;
  return (u16)r;
}
__device__ __forceinline__ short f2bf_s(float f) { return (short)f2bf(f); }

__device__ __forceinline__ void gld_lds16(const void* g, void* l) {
  __builtin_amdgcn_global_load_lds(
      (const __attribute__((address_space(1))) void*)g,
      (__attribute__((address_space(3))) void*)l, 16, 0, 0);
}

// single-use software grid barrier (counter pre-zeroed per launch)
__device__ __forceinline__ void gridbar(unsigned* ctr) {
  __syncthreads();  // all block stores complete (vmcnt drained)
  if (threadIdx.x == 0) {
    __hip_atomic_fetch_add(ctr, 1u, __ATOMIC_ACQ_REL, __HIP_MEMORY_SCOPE_AGENT);
    while (__hip_atomic_load(ctr, __ATOMIC_ACQUIRE, __HIP_MEMORY_SCOPE_AGENT) < NB)
      __builtin_amdgcn_s_sleep(2);
  }
  __syncthreads();
}

// ---------------- fp32 -> bf16 bulk conversion (RTN) ----------------
__global__ __launch_bounds__(256) void k_f32_to_bf16(
    const float* __restrict__ src, u16* __restrict__ dst, int n8) {
  int i = blockIdx.x * 256 + threadIdx.x;
  int stride = gridDim.x * 256;
  const float4* s = (const float4*)src;
  uint4* d = (uint4*)dst;
  for (; i < n8; i += stride) {
    float4 a = s[2 * i], b = s[2 * i + 1];
    uint4 o;
    o.x = f2bf(a.x) | ((unsigned)f2bf(a.y) << 16);
    o.y = f2bf(a.z) | ((unsigned)f2bf(a.w) << 16);
    o.z = f2bf(b.x) | ((unsigned)f2bf(b.y) << 16);
    o.w = f2bf(b.z) | ((unsigned)f2bf(b.w) << 16);
    d[i] = o;
  }
}

// ---------------- combined bias: b_ih + b_hh, 4 layers ----------------
__global__ __launch_bounds__(256) void k_bias(
    const float* __restrict__ bih0, const float* __restrict__ bhh0,
    const float* __restrict__ bihr, const float* __restrict__ bhhr,
    float* __restrict__ bias) {
  int i = blockIdx.x * 256 + threadIdx.x;
  if (i >= 4 * G4) return;
  int l = i >> 13, j = i & (G4 - 1);
  float a = (l == 0) ? bih0[j] : bihr[(l - 1) * G4 + j];
  float b = (l == 0) ? bhh0[j] : bhhr[(l - 1) * G4 + j];
  bias[i] = a + b;
}

// ---------------- stage x [B,T,D0] fp32 -> A [t*B+b, D0] bf16 ----------------
__global__ __launch_bounds__(256) void k_stage_x(
    const float* __restrict__ x, u16* __restrict__ A) {
  int i = blockIdx.x * 256 + threadIdx.x;
  if (i >= (B_ * T_ * D0) / 8) return;
  int chunk = i & (D0 / 8 - 1);
  int r = i >> 7;
  int b = r & (B_ - 1), t = r >> 6;
  const float4* s = (const float4*)(x + ((size_t)(b * T_ + t)) * D0 + chunk * 8);
  float4 a0 = s[0], a1 = s[1];
  uint4 o;
  o.x = f2bf(a0.x) | ((unsigned)f2bf(a0.y) << 16);
  o.y = f2bf(a0.z) | ((unsigned)f2bf(a0.w) << 16);
  o.z = f2bf(a1.x) | ((unsigned)f2bf(a1.y) << 16);
  o.w = f2bf(a1.z) | ((unsigned)f2bf(a1.w) << 16);
  *(uint4*)(A + (size_t)r * D0 + chunk * 8) = o;
}

// ---------------- input-projection GEMM (validated round 1) ----------------
__global__ __launch_bounds__(256) void k_gemm_xi(
    const u16* __restrict__ A, const u16* __restrict__ W,
    const float* __restrict__ bias, float* __restrict__ C, int K) {
  __shared__ __align__(16) u16 sA[128 * 32];
  __shared__ __align__(16) u16 sB[128 * 32];
  const int tid = threadIdx.x;
  const int wave = tid >> 6;
  const int lane = tid & 63;
  const int m0 = blockIdx.y * 128;
  const int n0 = blockIdx.x * 128;
  const int wr = wave >> 1, wc = wave & 1;
  const int lr = lane & 15;
  const int kc = (lane >> 4) * 8;
  const int rowA = tid >> 2, colk = (tid & 3) * 8;

  f32x4 acc[4][4] = {};

  for (int k0 = 0; k0 < K; k0 += 32) {
#pragma unroll
    for (int iss = 0; iss < 2; ++iss) {
      gld_lds16(A + (size_t)(m0 + iss * 64 + rowA) * K + k0 + colk,
                sA + (iss * 64 + wave * 16) * 32);
      gld_lds16(W + (size_t)(n0 + iss * 64 + rowA) * K + k0 + colk,
                sB + (iss * 64 + wave * 16) * 32);
    }
    __syncthreads();
    bf16x8 a[4], b[4];
#pragma unroll
    for (int m = 0; m < 4; ++m)
      a[m] = *(const bf16x8*)&sA[(wr * 64 + m * 16 + lr) * 32 + kc];
#pragma unroll
    for (int n = 0; n < 4; ++n)
      b[n] = *(const bf16x8*)&sB[(wc * 64 + n * 16 + lr) * 32 + kc];
#pragma unroll
    for (int m = 0; m < 4; ++m)
#pragma unroll
      for (int n = 0; n < 4; ++n)
        acc[m][n] = __builtin_amdgcn_mfma_f32_16x16x32_bf16(a[m], b[n], acc[m][n], 0, 0, 0);
    __syncthreads();
  }

#pragma unroll
  for (int n = 0; n < 4; ++n) {
    int col = n0 + wc * 64 + n * 16 + lr;
    float bv = bias[col];
#pragma unroll
    for (int m = 0; m < 4; ++m) {
      int rbase = m0 + wr * 64 + m * 16 + ((lane >> 4) << 2);
#pragma unroll
      for (int j = 0; j < 4; ++j)
        C[(size_t)(rbase + j) * G4 + col] = acc[m][n][j] + bv;
    }
  }
}

// ---------------- persistent per-layer recurrent kernel ----------------
// 256 blocks x 256 thr (1/CU, co-resident). Block owns 8 hidden units
// (32 gate rows); waves K-split (512 each); Whh bf16 B-fragments resident
// in VGPRs (converted from fp32 on load). Software grid barrier per step.
__global__ __launch_bounds__(256, 1) void k_lstm_seq(
    const float* __restrict__ whh,   // [8192][2048] fp32
    const float* __restrict__ xi,    // [T*B][8192] fp32 (bias folded)
    u16* __restrict__ hseq,          // [T*B][2048] bf16 out (next layer's A)
    float* __restrict__ out32,       // null, or [B][T][2048] fp32 (final out)
    unsigned* __restrict__ bar) {    // 15 pre-zeroed counters
  __shared__ float red[3][64][32];
  __shared__ float gbuf[64][32];
  __shared__ u16 harr[64][8];
  __shared__ float hfar[64][8];

  const int tid = threadIdx.x;
  const int wave = tid >> 6;  // K-slice index 0..3
  const int lane = tid & 63;
  const int lr = lane & 15;
  const int kc = lane >> 4;  // 0..3
  const int jb = blockIdx.x * 8;

  // ---- weight preload: fp32 global -> bf16 fragments in VGPRs ----
  bf16x8 warr[2][16];
#pragma unroll
  for (int n = 0; n < 2; ++n) {
    int row = n * 16 + lr;                          // 0..31: gate g=row>>3, j=row&7
    int grow = (row >> 3) * H_ + jb + (row & 7);    // global gate row
    const float* wp = whh + (size_t)grow * H_ + wave * 512 + kc * 8;
#pragma unroll
    for (int kk = 0; kk < 16; ++kk) {
      float4 f0 = *(const float4*)(wp + kk * 32);
      float4 f1 = *(const float4*)(wp + kk * 32 + 4);
      bf16x8 w;
      w[0] = f2bf_s(f0.x); w[1] = f2bf_s(f0.y); w[2] = f2bf_s(f0.z); w[3] = f2bf_s(f0.w);
      w[4] = f2bf_s(f1.x); w[5] = f2bf_s(f1.y); w[6] = f2bf_s(f1.z); w[7] = f2bf_s(f1.w);
      warr[n][kk] = w;
    }
  }

  const int p0 = tid * 2;
  const int b0_ = p0 >> 3, j0_ = p0 & 7;
  const int b1_ = (p0 + 1) >> 3, j1_ = (p0 + 1) & 7;
  float cst0 = 0.f, cst1 = 0.f;

  for (int t = 0; t < T_; ++t) {
    if (t > 0) gridbar(bar + (t - 1));  // h(t-1) visible device-wide

    // xi for this thread's two (b,j) pairs
    float xv0[4], xv1[4];
#pragma unroll
    for (int g = 0; g < 4; ++g) {
      xv0[g] = xi[(size_t)(t * B_ + b0_) * G4 + g * H_ + jb + j0_];
      xv1[g] = xi[(size_t)(t * B_ + b1_) * G4 + g * H_ + jb + j1_];
    }

    f32x4 acc[4][2] = {};
    if (t > 0) {
      const u16* hb = hseq + (size_t)(t - 1) * B_ * H_ +
                      (size_t)lr * H_ + wave * 512 + kc * 8;
#pragma unroll
      for (int kk = 0; kk < 16; ++kk) {
        bf16x8 af[4];
#pragma unroll
        for (int m = 0; m < 4; ++m)
          af[m] = *(const bf16x8*)(hb + (size_t)m * 16 * H_ + kk * 32);
#pragma unroll
        for (int m = 0; m < 4; ++m) {
          acc[m][0] = __builtin_amdgcn_mfma_f32_16x16x32_bf16(af[m], warr[0][kk], acc[m][0], 0, 0, 0);
          acc[m][1] = __builtin_amdgcn_mfma_f32_16x16x32_bf16(af[m], warr[1][kk], acc[m][1], 0, 0, 0);
        }
      }
    }

    // ---- cross-wave K reduction ----
    if (wave > 0) {
#pragma unroll
      for (int m = 0; m < 4; ++m)
#pragma unroll
        for (int n = 0; n < 2; ++n)
#pragma unroll
          for (int j = 0; j < 4; ++j)
            red[wave - 1][m * 16 + kc * 4 + j][n * 16 + lr] = acc[m][n][j];
    }
    __syncthreads();
    if (wave == 0) {
#pragma unroll
      for (int m = 0; m < 4; ++m)
#pragma unroll
        for (int n = 0; n < 2; ++n)
#pragma unroll
          for (int j = 0; j < 4; ++j) {
            int b = m * 16 + kc * 4 + j, r = n * 16 + lr;
            gbuf[b][r] = acc[m][n][j] + red[0][b][r] + red[1][b][r] + red[2][b][r];
          }
    }
    __syncthreads();

    // ---- LSTM cell: two (b,j) pairs per thread, c in registers ----
    {
      float iv = gbuf[b0_][j0_] + xv0[0];
      float fv = gbuf[b0_][8 + j0_] + xv0[1];
      float gv = gbuf[b0_][16 + j0_] + xv0[2];
      float ov = gbuf[b0_][24 + j0_] + xv0[3];
      iv = 1.f / (1.f + expf(-iv));
      fv = 1.f / (1.f + expf(-fv));
      gv = tanhf(gv);
      ov = 1.f / (1.f + expf(-ov));
      cst0 = fv * cst0 + iv * gv;
      float hv = ov * tanhf(cst0);
      harr[b0_][j0_] = f2bf(hv);
      hfar[b0_][j0_] = hv;
    }
    {
      float iv = gbuf[b1_][j1_] + xv1[0];
      float fv = gbuf[b1_][8 + j1_] + xv1[1];
      float gv = gbuf[b1_][16 + j1_] + xv1[2];
      float ov = gbuf[b1_][24 + j1_] + xv1[3];
      iv = 1.f / (1.f + expf(-iv));
      fv = 1.f / (1.f + expf(-fv));
      gv = tanhf(gv);
      ov = 1.f / (1.f + expf(-ov));
      cst1 = fv * cst1 + iv * gv;
      float hv = ov * tanhf(cst1);
      harr[b1_][j1_] = f2bf(hv);
      hfar[b1_][j1_] = hv;
    }
    __syncthreads();

    // ---- coalesced stores: 16B bf16 row-chunk per batch ----
    if (tid < B_) {
      *(uint4*)(hseq + (size_t)(t * B_ + tid) * H_ + jb) = *(const uint4*)&harr[tid][0];
      if (out32 != nullptr) {
        float* op = out32 + ((size_t)tid * T_ + t) * H_ + jb;
        *(float4*)op = *(const float4*)&hfar[tid][0];
        *(float4*)(op + 4) = *(const float4*)&hfar[tid][4];
      }
    }
  }
}

extern "C" void kernel_launch(void* const* d_in, const int* in_sizes, int n_in,
                              void* d_out, int out_size, void* d_ws, size_t ws_size,
                              hipStream_t stream) {
  const float* x    = (const float*)d_in[0];
  const float* wih0 = (const float*)d_in[1];
  const float* whh0 = (const float*)d_in[2];
  const float* bih0 = (const float*)d_in[3];
  const float* bhh0 = (const float*)d_in[4];
  const float* wihr = (const float*)d_in[5];
  const float* whhr = (const float*)d_in[6];
  const float* bihr = (const float*)d_in[7];
  const float* bhhr = (const float*)d_in[8];
  float* out = (float*)d_out;

  char* ws = (char*)d_ws;
  size_t off = 0;
  auto alloc = [&](size_t bytes) -> void* {
    void* p = ws + off;
    off += (bytes + 255) & ~(size_t)255;
    return p;
  };
  u16*      wih_b = (u16*)alloc(((size_t)G4 * D0 + 3ull * G4 * H_) * 2);
  float*    bias  = (float*)alloc(4ull * G4 * 4);
  float*    xi    = (float*)alloc((size_t)T_ * B_ * G4 * 4);
  u16*      Ax    = (u16*)alloc((size_t)T_ * B_ * D0 * 2);
  u16*      bufA  = (u16*)alloc((size_t)T_ * B_ * H_ * 2);
  u16*      bufB  = (u16*)alloc((size_t)T_ * B_ * H_ * 2);
  unsigned* bars  = (unsigned*)alloc(4 * 16 * sizeof(unsigned));

  u16* wih_r_b = wih_b + (size_t)G4 * D0;

  auto cgrid = [](int n8) { int g = (n8 + 255) / 256; return g > 8192 ? 8192 : g; };

  hipMemsetAsync(bars, 0, 4 * 16 * sizeof(unsigned), stream);

  int n8 = (G4 * D0) / 8;
  k_f32_to_bf16<<<cgrid(n8), 256, 0, stream>>>(wih0, wih_b, n8);
  n8 = (3 * G4 * H_) / 8;
  k_f32_to_bf16<<<cgrid(n8), 256, 0, stream>>>(wihr, wih_r_b, n8);

  k_bias<<<(4 * G4 + 255) / 256, 256, 0, stream>>>(bih0, bhh0, bihr, bhhr, bias);
  k_stage_x<<<((B_ * T_ * D0) / 8 + 255) / 256, 256, 0, stream>>>(x, Ax);

  const u16* Ain = Ax;
  for (int l = 0; l < 4; ++l) {
    const u16* W_ih = (l == 0) ? wih_b : (wih_r_b + (size_t)(l - 1) * G4 * H_);
    int K = (l == 0) ? D0 : H_;
    dim3 g(G4 / 128, (T_ * B_) / 128);
    k_gemm_xi<<<g, 256, 0, stream>>>(Ain, W_ih, bias + (size_t)l * G4, xi, K);

    const float* whh_l = (l == 0) ? whh0 : (whhr + (size_t)(l - 1) * G4 * H_);
    u16* Aout = (l & 1) ? bufB : bufA;
    float* o32 = (l == 3) ? out : nullptr;

    k_lstm_seq<<<NB, 256, 0, stream>>>(whh_l, xi, Aout, o32, bars + l * 16);
    Ain = Aout;
  }
}